// Round 11
// baseline (1445.932 us; speedup 1.0000x reference)
//
#include <hip/hip_runtime.h>

#define NN  100000
#define EE1 1600000
#define EE2 1600000

typedef unsigned short u16;
typedef unsigned int   u32;
typedef short s16x8 __attribute__((ext_vector_type(8)));
typedef float f32x4 __attribute__((ext_vector_type(4)));

__device__ __forceinline__ float bf2f(u32 u) {
    union { u32 i; float f; } v; v.i = (u & 0xffffu) << 16; return v.f;
}
__device__ __forceinline__ u16 f2bf(float f) {
    u32 x = __builtin_bit_cast(u32, f);
    return (u16)((x + 0x7fffu + ((x >> 16) & 1u)) >> 16);
}
__device__ __forceinline__ u32 pack2(float a, float b) {
    return (u32)f2bf(a) | ((u32)f2bf(b) << 16);
}
__device__ __forceinline__ int clampi(int v, int hi) {
    return v < 0 ? 0 : (v > hi ? hi : v);
}

// ---------------- CSR build (by dst) ----------------
__global__ void k_deg(const int* __restrict__ dst, int* __restrict__ deg) {
    int e = blockIdx.x * 256 + threadIdx.x;
    if (e < EE1) atomicAdd(&deg[clampi(dst[e], NN - 1)], 1);
}

__global__ void k_scan(const int* __restrict__ deg, int* __restrict__ offs, int* __restrict__ cur) {
    __shared__ int part[1024];
    const int t = threadIdx.x;
    const int chunk = (NN + 1023) / 1024;
    int b = t * chunk, e = min(NN, b + chunk);
    int s = 0;
    for (int i = b; i < e; ++i) s += deg[i];
    part[t] = s;
    __syncthreads();
    for (int d = 1; d < 1024; d <<= 1) {
        int v = (t >= d) ? part[t - d] : 0;
        __syncthreads();
        part[t] += v;
        __syncthreads();
    }
    int run = (t == 0) ? 0 : part[t - 1];
    for (int i = b; i < e; ++i) {
        offs[i] = run; cur[i] = run;
        run += deg[i];
    }
    if (t == 0) offs[NN] = EE1;
}

__global__ void k_fill(const int* __restrict__ src, const int* __restrict__ dst,
                       int* __restrict__ cur, int* __restrict__ csr) {
    int e = blockIdx.x * 256 + threadIdx.x;
    if (e < EE1) {
        int d = clampi(dst[e], NN - 1);
        int s = clampi(src[e], NN - 1);
        int p = atomicAdd(&cur[d], 1);
        if (p >= 0 && p < EE1) csr[p] = s;
    }
}

// ---------------- weight swizzle (fp32 sources) into MFMA B-fragment order ----------------
// WT[((c*KV + s)*64 + L)*8 + j] = W[k = s*32 + (L>>4)*8 + j][co = c*16 + (L&15)]
__global__ void k_prep(const float* __restrict__ Ws1, const float* __restrict__ Wn1,
                       const float* __restrict__ Ws2, const float* __restrict__ Wn2,
                       const float* __restrict__ Wm1,
                       u16* __restrict__ WT1, u16* __restrict__ WT2, u16* __restrict__ WTM) {
    int i = blockIdx.x * 256 + threadIdx.x;  // 65536 total
    if (i < 32768) {                          // WT1: Kv=256 ([Ws1;Wn1]), CO=128
        int f = i, j = f & 7, L = (f >> 3) & 63, t2 = f >> 9;
        int s = t2 & 7, c = t2 >> 3;
        int k = s * 32 + ((L >> 4) << 3) + j, co = (c << 4) + (L & 15);
        WT1[f] = f2bf((k < 128) ? Ws1[k * 128 + co] : Wn1[(k - 128) * 128 + co]);
    } else if (i < 49152) {                   // WT2: Kv=256 ([Ws2;Wn2]), CO=64
        int f = i - 32768, j = f & 7, L = (f >> 3) & 63, t2 = f >> 9;
        int s = t2 & 7, c = t2 >> 3;
        int k = s * 32 + ((L >> 4) << 3) + j, co = (c << 4) + (L & 15);
        WT2[f] = f2bf((k < 128) ? Ws2[k * 64 + co] : Wn2[(k - 128) * 64 + co]);
    } else {                                  // WTM: K=128, CO=128 (Wmlp1 straight)
        int f = i - 49152, j = f & 7, L = (f >> 3) & 63, t2 = f >> 9;
        int s = t2 & 3, c = t2 >> 2;
        int k = s * 32 + ((L >> 4) << 3) + j, co = (c << 4) + (L & 15);
        WTM[f] = f2bf(Wm1[k * 128 + co]);
    }
}

// ---------------- biases -> fp32 blob: [0:128)=b1, [128:192)=b2, [192:320)=bmlp1, [320:448)=Wmlp2, [448]=bmlp2
__global__ void k_bias(const float* b1, const float* b2, const float* bm1, const float* w2, const float* b2m,
                       float* __restrict__ blob) {
    const int t = threadIdx.x;
    if (t < 128)      blob[t] = b1[t];
    else if (t < 192) blob[t] = b2[t - 128];
    else if (t < 320) blob[t] = bm1[t - 192];
    else if (t < 448) blob[t] = w2[t - 320];
    else if (t == 448) blob[t] = b2m[0];
}

// ---------------- fused SAGE layer: H = relu([X | mean_agg(X)] @ [Wself;Wneigh] + b) ----------------
// FP32IN: X fp32 (layer 1) vs bf16 (layer 2). DUALOUT: also write fp32 h to Hf (final output).
template<int CO, bool FP32IN, bool DUALOUT>
__global__ __launch_bounds__(256) void k_layer(const void* __restrict__ Xv,
                                               const u16* __restrict__ WT,
                                               const int* __restrict__ offs,
                                               const int* __restrict__ csr,
                                               const float* __restrict__ biasf,
                                               u16* __restrict__ Hb,
                                               float* __restrict__ Hf) {
    constexpr int K = 128, KV = 8, CT = CO / 16, RS = K + 8;
    __shared__ __align__(16) u16 aggT[64 * RS];
    const int t = threadIdx.x, lane = t & 63, w = t >> 6;
    const int rbase = blockIdx.x * 64;
    const u16*   Xu = (const u16*)Xv;
    const float* Xf = (const float*)Xv;

    // phase A: pull-aggregate neighbor means into LDS (bf16)
    for (int i = 0; i < 16; ++i) {
        int lrow = w * 16 + i;
        int node = rbase + lrow;
        float a0 = 0.f, a1 = 0.f, sc = 0.f;
        if (node < NN) {
            int beg = offs[node], end = offs[node + 1];
            if (beg < 0) beg = 0;
            if (end > EE1) end = EE1;
            if (end < beg) end = beg;
            sc = 1.0f / (float)max(end - beg, 1);
            if (FP32IN) {
                for (int e = beg; e < end; ++e) {
                    int sn = clampi(csr[e], NN - 1);
                    float2 v = *(const float2*)&Xf[(size_t)sn * K + lane * 2];
                    a0 += v.x; a1 += v.y;
                }
            } else {
                for (int e = beg; e < end; ++e) {
                    int sn = clampi(csr[e], NN - 1);
                    u32 v = *(const u32*)&Xu[(size_t)sn * K + lane * 2];
                    a0 += bf2f(v); a1 += bf2f(v >> 16);
                }
            }
        }
        *(u32*)&aggT[lrow * RS + lane * 2] = pack2(a0 * sc, a1 * sc);
    }
    __syncthreads();

    // phase B: MFMA over virtual K=256 ([x_row | agg_row])
    const int nidx = lane & 15, quad = lane >> 4;
    int arow = rbase + w * 16 + nidx;
    if (arow > NN - 1) arow = NN - 1;          // clamped rows never stored
    s16x8 af[4];
    if (FP32IN) {
        const float* xf = &Xf[(size_t)arow * K];
#pragma unroll
        for (int s = 0; s < 4; ++s) {
            s16x8 tmp;
#pragma unroll
            for (int j = 0; j < 8; ++j) tmp[j] = (short)f2bf(xf[s * 32 + quad * 8 + j]);
            af[s] = tmp;
        }
    } else {
        const u16* xu = &Xu[(size_t)arow * K];
#pragma unroll
        for (int s = 0; s < 4; ++s) af[s] = *(const s16x8*)&xu[s * 32 + quad * 8];
    }
    const u16* grow = &aggT[(w * 16 + nidx) * RS];
    f32x4 acc[CT] = {};
#pragma unroll
    for (int s = 0; s < KV; ++s) {
        s16x8 a = (s < 4) ? af[s] : *(const s16x8*)&grow[(s - 4) * 32 + quad * 8];
#pragma unroll
        for (int c = 0; c < CT; ++c) {
            s16x8 b = *(const s16x8*)&WT[((c * KV + s) * 64 + lane) * 8];
            acc[c] = __builtin_amdgcn_mfma_f32_16x16x32_bf16(a, b, acc[c], 0, 0, 0);
        }
    }
#pragma unroll
    for (int c = 0; c < CT; ++c) {
        int col = c * 16 + nidx;
        float bv = biasf[col];
#pragma unroll
        for (int r = 0; r < 4; ++r) {
            int orow = rbase + w * 16 + quad * 4 + r;
            if (orow < NN) {
                float hv = fmaxf(acc[c][r] + bv, 0.f);
                Hb[(size_t)orow * CO + col] = f2bf(hv);
                if (DUALOUT) Hf[(size_t)orow * CO + col] = hv;   // fp32 h output
            }
        }
    }
}

// ---------------- edge scoring via MFMA from bf16 H2 copy; fp32 score output ----------------
__global__ __launch_bounds__(256) void k_edge(const u16* __restrict__ H2,
                                              const u16* __restrict__ WTM,
                                              const int* __restrict__ es, const int* __restrict__ ed,
                                              const float* __restrict__ blob,
                                              float* __restrict__ out) {
    constexpr int RS = 136;
    __shared__ __align__(16) u16 at[64 * RS];
    const int t = threadIdx.x, lane = t & 63, w = t >> 6;
    const int ebase = blockIdx.x * 64 + w * 16;
    {
        const int le = lane >> 2, p = lane & 3;
        const int e = ebase + le;
        int node = (p < 2) ? es[e] : ed[e];
        node = clampi(node, NN - 1);
        const u16* row = H2 + (size_t)node * 64 + (p & 1) * 32;
        u16* drow = &at[(w * 16 + le) * RS + (p >> 1) * 64 + (p & 1) * 32];
        *(uint4*)&drow[0]  = *(const uint4*)&row[0];
        *(uint4*)&drow[8]  = *(const uint4*)&row[8];
        *(uint4*)&drow[16] = *(const uint4*)&row[16];
        *(uint4*)&drow[24] = *(const uint4*)&row[24];
    }
    __syncthreads();

    const int nidx = lane & 15, quad = lane >> 4;
    const u16* arow = &at[(w * 16 + nidx) * RS];
    f32x4 acc[8] = {};
#pragma unroll
    for (int s = 0; s < 4; ++s) {
        s16x8 a = *(const s16x8*)&arow[s * 32 + quad * 8];
#pragma unroll
        for (int c = 0; c < 8; ++c) {
            s16x8 b = *(const s16x8*)&WTM[((c * 4 + s) * 64 + lane) * 8];
            acc[c] = __builtin_amdgcn_mfma_f32_16x16x32_bf16(a, b, acc[c], 0, 0, 0);
        }
    }
    float sum[4] = {0.f, 0.f, 0.f, 0.f};
#pragma unroll
    for (int c = 0; c < 8; ++c) {
        int col = c * 16 + nidx;
        float bb = blob[192 + col], ww = blob[320 + col];
#pragma unroll
        for (int r = 0; r < 4; ++r)
            sum[r] += fmaxf(acc[c][r] + bb, 0.f) * ww;
    }
#pragma unroll
    for (int r = 0; r < 4; ++r) {
        sum[r] += __shfl_xor(sum[r], 1, 64);
        sum[r] += __shfl_xor(sum[r], 2, 64);
        sum[r] += __shfl_xor(sum[r], 4, 64);
        sum[r] += __shfl_xor(sum[r], 8, 64);
    }
    if (nidx == 0) {
        float bb2 = blob[448];
#pragma unroll
        for (int r = 0; r < 4; ++r) {
            float x = sum[r] + bb2;
            out[ebase + quad * 4 + r] = 1.f / (1.f + __expf(-x));   // fp32 score
        }
    }
}

extern "C" void kernel_launch(void* const* d_in, const int* in_sizes, int n_in,
                              void* d_out, int out_size, void* d_ws, size_t ws_size,
                              hipStream_t stream) {
    const void*  X      = d_in[0];
    const int*   esrc   = (const int*)d_in[1];
    const int*   edst   = (const int*)d_in[2];
    const int*   ssrc   = (const int*)d_in[3];
    const int*   sdst   = (const int*)d_in[4];
    const float* Wself1 = (const float*)d_in[5];
    const float* Wneigh1= (const float*)d_in[6];
    const float* b1     = (const float*)d_in[7];
    const float* Wself2 = (const float*)d_in[8];
    const float* Wneigh2= (const float*)d_in[9];
    const float* b2     = (const float*)d_in[10];
    const float* Wmlp1  = (const float*)d_in[11];
    const float* bmlp1  = (const float*)d_in[12];
    const float* Wmlp2  = (const float*)d_in[13];
    const float* bmlp2  = (const float*)d_in[14];

    // ---- workspace (probe-verified ws_size >= 50 MB): peak 45.33 MB ----
    char* ws = (char*)d_ws;
    int*   offs = (int*)(ws + 0);             //   400,004 -> pad 400,128
    int*   csr  = (int*)(ws + 400128);        // 6,400,000 -> 6,800,128
    u16*   WTM  = (u16*)(ws + 6800128);       //    32,768 -> 6,832,896
    u16*   WT1  = (u16*)(ws + 6832896);       //    65,536 -> 6,898,432
    u16*   WT2  = (u16*)(ws + 6898432);       //    32,768 -> 6,931,200
    float* blob = (float*)(ws + 6931200);     //     1,796 -> pad 6,933,504
    u16*   H1   = (u16*)(ws + 6933504);       // 25,600,000 -> 32,533,504 (bf16 intern)
    u16*   H2b  = (u16*)(ws + 32533504);      // 12,800,000 -> 45,333,504 (bf16 copy of h)
    int*   deg  = (int*)(ws + 6933504);       // aliases H1 (dead before H1 written)
    int*   cur  = (int*)(ws + 7333504);       // aliases H1 + 400 KB

    // ---- OUTPUT: fp32 buffer, out_size=8M floats: [score 1.6M | h 6.4M] ----
    float* outScore = (float*)d_out;               // [EE2]
    float* Hf       = (float*)d_out + EE2;         // [NN*64]

    hipMemsetAsync(deg, 0, NN * sizeof(int), stream);
    k_deg <<<(EE1 + 255) / 256, 256, 0, stream>>>(edst, deg);
    k_scan<<<1, 1024, 0, stream>>>(deg, offs, cur);
    k_fill<<<(EE1 + 255) / 256, 256, 0, stream>>>(esrc, edst, cur, csr);
    k_prep<<<256, 256, 0, stream>>>(Wself1, Wneigh1, Wself2, Wneigh2, Wmlp1, WT1, WT2, WTM);
    k_bias<<<1, 512, 0, stream>>>(b1, b2, bmlp1, Wmlp2, bmlp2, blob);

    const int nblk = (NN + 63) / 64;
    k_layer<128, true,  false><<<nblk, 256, 0, stream>>>(X,  WT1, offs, csr, blob,       H1,  nullptr);
    k_layer<64,  false, true> <<<nblk, 256, 0, stream>>>(H1, WT2, offs, csr, blob + 128, H2b, Hf);
    k_edge<<<EE2 / 64, 256, 0, stream>>>(H2b, WTM, ssrc, sdst, blob, outScore);
}

// Round 12
// 874.803 us; speedup vs baseline: 1.6529x; 1.6529x over previous
//
#include <hip/hip_runtime.h>

#define NN  100000
#define EE1 1600000
#define EE2 1600000

typedef unsigned short u16;
typedef unsigned int   u32;
typedef short s16x8 __attribute__((ext_vector_type(8)));
typedef float f32x4 __attribute__((ext_vector_type(4)));

__device__ __forceinline__ float bf2f(u32 u) {
    union { u32 i; float f; } v; v.i = (u & 0xffffu) << 16; return v.f;
}
__device__ __forceinline__ u16 f2bf(float f) {
    u32 x = __builtin_bit_cast(u32, f);
    return (u16)((x + 0x7fffu + ((x >> 16) & 1u)) >> 16);
}
__device__ __forceinline__ u32 pack2(float a, float b) {
    return (u32)f2bf(a) | ((u32)f2bf(b) << 16);
}
__device__ __forceinline__ int clampi(int v, int hi) {
    return v < 0 ? 0 : (v > hi ? hi : v);
}

// ---------------- X -> bf16 cast (into d_out h-region, dead until layer 2) ----------------
__global__ void k_cast(const float* __restrict__ X, u16* __restrict__ Xb) {
    int i = blockIdx.x * 256 + threadIdx.x;      // 4 elements per thread
    if (i < NN * 128 / 4) {
        float4 v = *(const float4*)&X[i * 4];
        union { u16 h[4]; uint2 u; } o;
        o.h[0] = f2bf(v.x); o.h[1] = f2bf(v.y);
        o.h[2] = f2bf(v.z); o.h[3] = f2bf(v.w);
        *(uint2*)&Xb[i * 4] = o.u;
    }
}

// ---------------- CSR build (by dst) ----------------
__global__ void k_deg(const int* __restrict__ dst, int* __restrict__ deg) {
    int e = blockIdx.x * 256 + threadIdx.x;
    if (e < EE1) atomicAdd(&deg[clampi(dst[e], NN - 1)], 1);
}

__global__ void k_scan(const int* __restrict__ deg, int* __restrict__ offs, int* __restrict__ cur) {
    __shared__ int part[1024];
    const int t = threadIdx.x;
    const int chunk = (NN + 1023) / 1024;
    int b = t * chunk, e = min(NN, b + chunk);
    int s = 0;
    for (int i = b; i < e; ++i) s += deg[i];
    part[t] = s;
    __syncthreads();
    for (int d = 1; d < 1024; d <<= 1) {
        int v = (t >= d) ? part[t - d] : 0;
        __syncthreads();
        part[t] += v;
        __syncthreads();
    }
    int run = (t == 0) ? 0 : part[t - 1];
    for (int i = b; i < e; ++i) {
        offs[i] = run; cur[i] = run;
        run += deg[i];
    }
    if (t == 0) offs[NN] = EE1;
}

__global__ void k_fill(const int* __restrict__ src, const int* __restrict__ dst,
                       int* __restrict__ cur, int* __restrict__ csr) {
    int e = blockIdx.x * 256 + threadIdx.x;
    if (e < EE1) {
        int d = clampi(dst[e], NN - 1);
        int s = clampi(src[e], NN - 1);
        int p = atomicAdd(&cur[d], 1);
        if (p >= 0 && p < EE1) csr[p] = s;
    }
}

// ---------------- weight swizzle (fp32 sources) into MFMA B-fragment order ----------------
__global__ void k_prep(const float* __restrict__ Ws1, const float* __restrict__ Wn1,
                       const float* __restrict__ Ws2, const float* __restrict__ Wn2,
                       const float* __restrict__ Wm1,
                       u16* __restrict__ WT1, u16* __restrict__ WT2, u16* __restrict__ WTM) {
    int i = blockIdx.x * 256 + threadIdx.x;  // 65536 total
    if (i < 32768) {                          // WT1: Kv=256 ([Ws1;Wn1]), CO=128
        int f = i, j = f & 7, L = (f >> 3) & 63, t2 = f >> 9;
        int s = t2 & 7, c = t2 >> 3;
        int k = s * 32 + ((L >> 4) << 3) + j, co = (c << 4) + (L & 15);
        WT1[f] = f2bf((k < 128) ? Ws1[k * 128 + co] : Wn1[(k - 128) * 128 + co]);
    } else if (i < 49152) {                   // WT2: Kv=256 ([Ws2;Wn2]), CO=64
        int f = i - 32768, j = f & 7, L = (f >> 3) & 63, t2 = f >> 9;
        int s = t2 & 7, c = t2 >> 3;
        int k = s * 32 + ((L >> 4) << 3) + j, co = (c << 4) + (L & 15);
        WT2[f] = f2bf((k < 128) ? Ws2[k * 64 + co] : Wn2[(k - 128) * 64 + co]);
    } else {                                  // WTM: K=128, CO=128 (Wmlp1 straight)
        int f = i - 49152, j = f & 7, L = (f >> 3) & 63, t2 = f >> 9;
        int s = t2 & 3, c = t2 >> 2;
        int k = s * 32 + ((L >> 4) << 3) + j, co = (c << 4) + (L & 15);
        WTM[f] = f2bf(Wm1[k * 128 + co]);
    }
}

// ---------------- biases -> fp32 blob ----------------
__global__ void k_bias(const float* b1, const float* b2, const float* bm1, const float* w2, const float* b2m,
                       float* __restrict__ blob) {
    const int t = threadIdx.x;
    if (t < 128)      blob[t] = b1[t];
    else if (t < 192) blob[t] = b2[t - 128];
    else if (t < 320) blob[t] = bm1[t - 192];
    else if (t < 448) blob[t] = w2[t - 320];
    else if (t == 448) blob[t] = b2m[0];
}

__device__ __forceinline__ void acc8(float* a, uint4 r) {
    a[0] += bf2f(r.x); a[1] += bf2f(r.x >> 16);
    a[2] += bf2f(r.y); a[3] += bf2f(r.y >> 16);
    a[4] += bf2f(r.z); a[5] += bf2f(r.z >> 16);
    a[6] += bf2f(r.w); a[7] += bf2f(r.w >> 16);
}

// ---------------- fused SAGE layer (bf16 in): H = relu([X | mean_agg(X)] @ [Ws;Wn] + b) ----------------
// Phase A: quarter-wave per node (4 nodes in flight per wave), thread owns 8 features,
//          edge loop unrolled x4 -> up to 16 independent gather chains per wave.
template<int CO, bool DUALOUT>
__global__ __launch_bounds__(256) void k_layer(const u16* __restrict__ Xb,
                                               const u16* __restrict__ WT,
                                               const int* __restrict__ offs,
                                               const int* __restrict__ csr,
                                               const float* __restrict__ biasf,
                                               u16* __restrict__ Hb,
                                               float* __restrict__ Hf) {
    constexpr int K = 128, KV = 8, CT = CO / 16, RS = K + 8;
    __shared__ __align__(16) u16 aggT[64 * RS];
    const int t = threadIdx.x, lane = t & 63, w = t >> 6;
    const int g = lane >> 4, f = lane & 15;     // group 0..3, feature slot (8 feats)
    const int rbase = blockIdx.x * 64;

    // phase A: pull-aggregate neighbor means into LDS (bf16)
    for (int i = 0; i < 4; ++i) {
        const int lrow = w * 16 + i * 4 + g;
        const int node = rbase + lrow;
        float acc[8] = {0.f, 0.f, 0.f, 0.f, 0.f, 0.f, 0.f, 0.f};
        float sc = 0.f;
        if (node < NN) {
            int beg = offs[node], end = offs[node + 1];
            if (beg < 0) beg = 0;
            if (end > EE1) end = EE1;
            if (end < beg) end = beg;
            sc = 1.0f / (float)max(end - beg, 1);
            int e = beg;
            for (; e + 4 <= end; e += 4) {
                int n0 = clampi(csr[e],     NN - 1);
                int n1 = clampi(csr[e + 1], NN - 1);
                int n2 = clampi(csr[e + 2], NN - 1);
                int n3 = clampi(csr[e + 3], NN - 1);
                uint4 r0 = *(const uint4*)&Xb[(size_t)n0 * K + f * 8];
                uint4 r1 = *(const uint4*)&Xb[(size_t)n1 * K + f * 8];
                uint4 r2 = *(const uint4*)&Xb[(size_t)n2 * K + f * 8];
                uint4 r3 = *(const uint4*)&Xb[(size_t)n3 * K + f * 8];
                acc8(acc, r0); acc8(acc, r1); acc8(acc, r2); acc8(acc, r3);
            }
            for (; e < end; ++e) {
                int n = clampi(csr[e], NN - 1);
                uint4 r = *(const uint4*)&Xb[(size_t)n * K + f * 8];
                acc8(acc, r);
            }
        }
        uint4 o;
        o.x = pack2(acc[0] * sc, acc[1] * sc);
        o.y = pack2(acc[2] * sc, acc[3] * sc);
        o.z = pack2(acc[4] * sc, acc[5] * sc);
        o.w = pack2(acc[6] * sc, acc[7] * sc);
        *(uint4*)&aggT[lrow * RS + f * 8] = o;
    }
    __syncthreads();

    // phase B: MFMA over virtual K=256 ([x_row | agg_row])
    const int nidx = lane & 15, quad = lane >> 4;
    int arow = rbase + w * 16 + nidx;
    if (arow > NN - 1) arow = NN - 1;          // clamped rows never stored
    const u16* xu = &Xb[(size_t)arow * K];
    const u16* grow = &aggT[(w * 16 + nidx) * RS];
    f32x4 acc[CT] = {};
#pragma unroll
    for (int s = 0; s < KV; ++s) {
        s16x8 a = (s < 4) ? *(const s16x8*)&xu[s * 32 + quad * 8]
                          : *(const s16x8*)&grow[(s - 4) * 32 + quad * 8];
#pragma unroll
        for (int c = 0; c < CT; ++c) {
            s16x8 b = *(const s16x8*)&WT[((c * KV + s) * 64 + lane) * 8];
            acc[c] = __builtin_amdgcn_mfma_f32_16x16x32_bf16(a, b, acc[c], 0, 0, 0);
        }
    }
#pragma unroll
    for (int c = 0; c < CT; ++c) {
        int col = c * 16 + nidx;
        float bv = biasf[col];
#pragma unroll
        for (int r = 0; r < 4; ++r) {
            int orow = rbase + w * 16 + quad * 4 + r;
            if (orow < NN) {
                float hv = fmaxf(acc[c][r] + bv, 0.f);
                Hb[(size_t)orow * CO + col] = f2bf(hv);
                if (DUALOUT) Hf[(size_t)orow * CO + col] = hv;   // fp32 h output
            }
        }
    }
}

// ---------------- edge scoring via MFMA from bf16 H2 copy; fp32 score output ----------------
__global__ __launch_bounds__(256) void k_edge(const u16* __restrict__ H2,
                                              const u16* __restrict__ WTM,
                                              const int* __restrict__ es, const int* __restrict__ ed,
                                              const float* __restrict__ blob,
                                              float* __restrict__ out) {
    constexpr int RS = 136;
    __shared__ __align__(16) u16 at[64 * RS];
    const int t = threadIdx.x, lane = t & 63, w = t >> 6;
    const int ebase = blockIdx.x * 64 + w * 16;
    {
        const int le = lane >> 2, p = lane & 3;
        const int e = ebase + le;
        int node = (p < 2) ? es[e] : ed[e];
        node = clampi(node, NN - 1);
        const u16* row = H2 + (size_t)node * 64 + (p & 1) * 32;
        u16* drow = &at[(w * 16 + le) * RS + (p >> 1) * 64 + (p & 1) * 32];
        *(uint4*)&drow[0]  = *(const uint4*)&row[0];
        *(uint4*)&drow[8]  = *(const uint4*)&row[8];
        *(uint4*)&drow[16] = *(const uint4*)&row[16];
        *(uint4*)&drow[24] = *(const uint4*)&row[24];
    }
    __syncthreads();

    const int nidx = lane & 15, quad = lane >> 4;
    const u16* arow = &at[(w * 16 + nidx) * RS];
    f32x4 acc[8] = {};
#pragma unroll
    for (int s = 0; s < 4; ++s) {
        s16x8 a = *(const s16x8*)&arow[s * 32 + quad * 8];
#pragma unroll
        for (int c = 0; c < 8; ++c) {
            s16x8 b = *(const s16x8*)&WTM[((c * 4 + s) * 64 + lane) * 8];
            acc[c] = __builtin_amdgcn_mfma_f32_16x16x32_bf16(a, b, acc[c], 0, 0, 0);
        }
    }
    float sum[4] = {0.f, 0.f, 0.f, 0.f};
#pragma unroll
    for (int c = 0; c < 8; ++c) {
        int col = c * 16 + nidx;
        float bb = blob[192 + col], ww = blob[320 + col];
#pragma unroll
        for (int r = 0; r < 4; ++r)
            sum[r] += fmaxf(acc[c][r] + bb, 0.f) * ww;
    }
#pragma unroll
    for (int r = 0; r < 4; ++r) {
        sum[r] += __shfl_xor(sum[r], 1, 64);
        sum[r] += __shfl_xor(sum[r], 2, 64);
        sum[r] += __shfl_xor(sum[r], 4, 64);
        sum[r] += __shfl_xor(sum[r], 8, 64);
    }
    if (nidx == 0) {
        float bb2 = blob[448];
#pragma unroll
        for (int r = 0; r < 4; ++r) {
            float x = sum[r] + bb2;
            out[ebase + quad * 4 + r] = 1.f / (1.f + __expf(-x));   // fp32 score
        }
    }
}

extern "C" void kernel_launch(void* const* d_in, const int* in_sizes, int n_in,
                              void* d_out, int out_size, void* d_ws, size_t ws_size,
                              hipStream_t stream) {
    const float* X      = (const float*)d_in[0];
    const int*   esrc   = (const int*)d_in[1];
    const int*   edst   = (const int*)d_in[2];
    const int*   ssrc   = (const int*)d_in[3];
    const int*   sdst   = (const int*)d_in[4];
    const float* Wself1 = (const float*)d_in[5];
    const float* Wneigh1= (const float*)d_in[6];
    const float* b1     = (const float*)d_in[7];
    const float* Wself2 = (const float*)d_in[8];
    const float* Wneigh2= (const float*)d_in[9];
    const float* b2     = (const float*)d_in[10];
    const float* Wmlp1  = (const float*)d_in[11];
    const float* bmlp1  = (const float*)d_in[12];
    const float* Wmlp2  = (const float*)d_in[13];
    const float* bmlp2  = (const float*)d_in[14];

    // ---- workspace (probe-verified ws_size >= 50 MB): peak 45.33 MB ----
    char* ws = (char*)d_ws;
    int*   offs = (int*)(ws + 0);             //   400,004 -> pad 400,128
    int*   csr  = (int*)(ws + 400128);        // 6,400,000 -> 6,800,128
    u16*   WTM  = (u16*)(ws + 6800128);       //    32,768 -> 6,832,896
    u16*   WT1  = (u16*)(ws + 6832896);       //    65,536 -> 6,898,432
    u16*   WT2  = (u16*)(ws + 6898432);       //    32,768 -> 6,931,200
    float* blob = (float*)(ws + 6931200);     //     1,796 -> pad 6,933,504
    u16*   H1   = (u16*)(ws + 6933504);       // 25,600,000 -> 32,533,504 (bf16 intern)
    u16*   H2b  = (u16*)(ws + 32533504);      // 12,800,000 -> 45,333,504 (bf16 copy of h)
    int*   deg  = (int*)(ws + 6933504);       // aliases H1 (dead before H1 written)
    int*   cur  = (int*)(ws + 7333504);       // aliases H1 + 400 KB

    // ---- OUTPUT: fp32 buffer, out_size=8M floats: [score 1.6M | h 6.4M] ----
    float* outScore = (float*)d_out;               // [EE2]
    float* Hf       = (float*)d_out + EE2;         // [NN*64]
    // X as bf16, parked in d_out's h-region (dead until layer-2's Hf write):
    u16*   Xb       = (u16*)((char*)d_out + 6400000);   // 25.6 MB, ends at 32 MB

    k_cast<<<(NN * 128 / 4 + 255) / 256, 256, 0, stream>>>(X, Xb);
    hipMemsetAsync(deg, 0, NN * sizeof(int), stream);
    k_deg <<<(EE1 + 255) / 256, 256, 0, stream>>>(edst, deg);
    k_scan<<<1, 1024, 0, stream>>>(deg, offs, cur);
    k_fill<<<(EE1 + 255) / 256, 256, 0, stream>>>(esrc, edst, cur, csr);
    k_prep<<<256, 256, 0, stream>>>(Wself1, Wneigh1, Wself2, Wneigh2, Wmlp1, WT1, WT2, WTM);
    k_bias<<<1, 512, 0, stream>>>(b1, b2, bmlp1, Wmlp2, bmlp2, blob);

    const int nblk = (NN + 63) / 64;
    k_layer<128, false><<<nblk, 256, 0, stream>>>(Xb, WT1, offs, csr, blob,       H1,  nullptr);
    k_layer<64,  true> <<<nblk, 256, 0, stream>>>(H1, WT2, offs, csr, blob + 128, H2b, Hf);
    k_edge<<<EE2 / 64, 256, 0, stream>>>(H2b, WTM, ssrc, sdst, blob, outScore);
}

// Round 13
// 650.638 us; speedup vs baseline: 2.2223x; 1.3445x over previous
//
#include <hip/hip_runtime.h>

#define NN  100000
#define EE1 1600000
#define EE2 1600000
#define NBLK_SCAN ((NN + 255) / 256)   // 391

typedef unsigned short u16;
typedef unsigned int   u32;
typedef short s16x8 __attribute__((ext_vector_type(8)));
typedef float f32x4 __attribute__((ext_vector_type(4)));

__device__ __forceinline__ float bf2f(u32 u) {
    union { u32 i; float f; } v; v.i = (u & 0xffffu) << 16; return v.f;
}
__device__ __forceinline__ u16 f2bf(float f) {
    u32 x = __builtin_bit_cast(u32, f);
    return (u16)((x + 0x7fffu + ((x >> 16) & 1u)) >> 16);
}
__device__ __forceinline__ u32 pack2(float a, float b) {
    return (u32)f2bf(a) | ((u32)f2bf(b) << 16);
}
__device__ __forceinline__ int clampi(int v, int hi) {
    return v < 0 ? 0 : (v > hi ? hi : v);
}

// ---------------- X -> bf16 cast (into d_out h-region, dead until layer 2) ----------------
__global__ void k_cast(const float* __restrict__ X, u16* __restrict__ Xb) {
    int i = blockIdx.x * 256 + threadIdx.x;      // 4 elements per thread
    if (i < NN * 128 / 4) {
        float4 v = *(const float4*)&X[i * 4];
        union { u16 h[4]; uint2 u; } o;
        o.h[0] = f2bf(v.x); o.h[1] = f2bf(v.y);
        o.h[2] = f2bf(v.z); o.h[3] = f2bf(v.w);
        *(uint2*)&Xb[i * 4] = o.u;
    }
}

// ---------------- CSR build (by dst) ----------------
__global__ void k_deg(const int* __restrict__ dst, int* __restrict__ deg) {
    int e = blockIdx.x * 256 + threadIdx.x;
    if (e < EE1) atomicAdd(&deg[clampi(dst[e], NN - 1)], 1);
}

// device-wide exclusive scan, 3 phases
__global__ void k_scan1(const int* __restrict__ deg, int* __restrict__ part) {
    __shared__ int l[256];
    const int t = threadIdx.x;
    int i = blockIdx.x * 256 + t;
    l[t] = (i < NN) ? deg[i] : 0;
    __syncthreads();
    for (int d = 128; d > 0; d >>= 1) {
        if (t < d) l[t] += l[t + d];
        __syncthreads();
    }
    if (t == 0) part[blockIdx.x] = l[0];
}

__global__ void k_scan2(int* __restrict__ part) {
    __shared__ int l[512];
    const int t = threadIdx.x;
    l[t] = (t < NBLK_SCAN) ? part[t] : 0;
    __syncthreads();
    for (int d = 1; d < 512; d <<= 1) {
        int v = (t >= d) ? l[t - d] : 0;
        __syncthreads();
        l[t] += v;
        __syncthreads();
    }
    if (t < NBLK_SCAN) part[t] = (t == 0) ? 0 : l[t - 1];   // exclusive
}

__global__ void k_scan3(const int* __restrict__ deg, const int* __restrict__ part,
                        int* __restrict__ offs, int* __restrict__ cur) {
    __shared__ int l[256];
    const int t = threadIdx.x;
    const int i = blockIdx.x * 256 + t;
    const int v = (i < NN) ? deg[i] : 0;
    l[t] = v;
    __syncthreads();
    for (int d = 1; d < 256; d <<= 1) {
        int x = (t >= d) ? l[t - d] : 0;
        __syncthreads();
        l[t] += x;
        __syncthreads();
    }
    int excl = l[t] - v + part[blockIdx.x];
    if (i < NN) { offs[i] = excl; cur[i] = excl; }
    if (i == NN - 1) offs[NN] = EE1;
}

__global__ void k_fill(const int* __restrict__ src, const int* __restrict__ dst,
                       int* __restrict__ cur, int* __restrict__ csr) {
    int e = blockIdx.x * 256 + threadIdx.x;
    if (e < EE1) {
        int d = clampi(dst[e], NN - 1);
        int s = clampi(src[e], NN - 1);
        int p = atomicAdd(&cur[d], 1);
        if (p >= 0 && p < EE1) csr[p] = s;
    }
}

// ---------------- weight swizzle (fp32 sources) into MFMA B-fragment order ----------------
__global__ void k_prep(const float* __restrict__ Ws1, const float* __restrict__ Wn1,
                       const float* __restrict__ Ws2, const float* __restrict__ Wn2,
                       const float* __restrict__ Wm1,
                       u16* __restrict__ WT1, u16* __restrict__ WT2, u16* __restrict__ WTM) {
    int i = blockIdx.x * 256 + threadIdx.x;  // 65536 total
    if (i < 32768) {                          // WT1: Kv=256 ([Ws1;Wn1]), CO=128
        int f = i, j = f & 7, L = (f >> 3) & 63, t2 = f >> 9;
        int s = t2 & 7, c = t2 >> 3;
        int k = s * 32 + ((L >> 4) << 3) + j, co = (c << 4) + (L & 15);
        WT1[f] = f2bf((k < 128) ? Ws1[k * 128 + co] : Wn1[(k - 128) * 128 + co]);
    } else if (i < 49152) {                   // WT2: Kv=256 ([Ws2;Wn2]), CO=64
        int f = i - 32768, j = f & 7, L = (f >> 3) & 63, t2 = f >> 9;
        int s = t2 & 7, c = t2 >> 3;
        int k = s * 32 + ((L >> 4) << 3) + j, co = (c << 4) + (L & 15);
        WT2[f] = f2bf((k < 128) ? Ws2[k * 64 + co] : Wn2[(k - 128) * 64 + co]);
    } else {                                  // WTM: K=128, CO=128 (Wmlp1 straight)
        int f = i - 49152, j = f & 7, L = (f >> 3) & 63, t2 = f >> 9;
        int s = t2 & 3, c = t2 >> 2;
        int k = s * 32 + ((L >> 4) << 3) + j, co = (c << 4) + (L & 15);
        WTM[f] = f2bf(Wm1[k * 128 + co]);
    }
}

// ---------------- biases -> fp32 blob ----------------
__global__ void k_bias(const float* b1, const float* b2, const float* bm1, const float* w2, const float* b2m,
                       float* __restrict__ blob) {
    const int t = threadIdx.x;
    if (t < 128)      blob[t] = b1[t];
    else if (t < 192) blob[t] = b2[t - 128];
    else if (t < 320) blob[t] = bm1[t - 192];
    else if (t < 448) blob[t] = w2[t - 320];
    else if (t == 448) blob[t] = b2m[0];
}

__device__ __forceinline__ void acc8(float* a, uint4 r) {
    a[0] += bf2f(r.x); a[1] += bf2f(r.x >> 16);
    a[2] += bf2f(r.y); a[3] += bf2f(r.y >> 16);
    a[4] += bf2f(r.z); a[5] += bf2f(r.z >> 16);
    a[6] += bf2f(r.w); a[7] += bf2f(r.w >> 16);
}

// ---------------- fused SAGE layer (bf16 in): H = relu([X | mean_agg(X)] @ [Ws;Wn] + b) ----------------
template<int CO, bool DUALOUT>
__global__ __launch_bounds__(256) void k_layer(const u16* __restrict__ Xb,
                                               const u16* __restrict__ WT,
                                               const int* __restrict__ offs,
                                               const int* __restrict__ csr,
                                               const float* __restrict__ biasf,
                                               u16* __restrict__ Hb,
                                               float* __restrict__ Hf) {
    constexpr int K = 128, KV = 8, CT = CO / 16, RS = K + 8;
    __shared__ __align__(16) u16 aggT[64 * RS];
    const int t = threadIdx.x, lane = t & 63, w = t >> 6;
    const int g = lane >> 4, f = lane & 15;     // group 0..3, feature slot (8 feats)
    const int rbase = blockIdx.x * 64;

    // phase A: pull-aggregate neighbor means into LDS (bf16)
    for (int i = 0; i < 4; ++i) {
        const int lrow = w * 16 + i * 4 + g;
        const int node = rbase + lrow;
        float acc[8] = {0.f, 0.f, 0.f, 0.f, 0.f, 0.f, 0.f, 0.f};
        float sc = 0.f;
        if (node < NN) {
            int beg = offs[node], end = offs[node + 1];
            if (beg < 0) beg = 0;
            if (end > EE1) end = EE1;
            if (end < beg) end = beg;
            sc = 1.0f / (float)max(end - beg, 1);
            int e = beg;
            for (; e + 4 <= end; e += 4) {
                int n0 = clampi(csr[e],     NN - 1);
                int n1 = clampi(csr[e + 1], NN - 1);
                int n2 = clampi(csr[e + 2], NN - 1);
                int n3 = clampi(csr[e + 3], NN - 1);
                uint4 r0 = *(const uint4*)&Xb[(size_t)n0 * K + f * 8];
                uint4 r1 = *(const uint4*)&Xb[(size_t)n1 * K + f * 8];
                uint4 r2 = *(const uint4*)&Xb[(size_t)n2 * K + f * 8];
                uint4 r3 = *(const uint4*)&Xb[(size_t)n3 * K + f * 8];
                acc8(acc, r0); acc8(acc, r1); acc8(acc, r2); acc8(acc, r3);
            }
            for (; e < end; ++e) {
                int n = clampi(csr[e], NN - 1);
                uint4 r = *(const uint4*)&Xb[(size_t)n * K + f * 8];
                acc8(acc, r);
            }
        }
        uint4 o;
        o.x = pack2(acc[0] * sc, acc[1] * sc);
        o.y = pack2(acc[2] * sc, acc[3] * sc);
        o.z = pack2(acc[4] * sc, acc[5] * sc);
        o.w = pack2(acc[6] * sc, acc[7] * sc);
        *(uint4*)&aggT[lrow * RS + f * 8] = o;
    }
    __syncthreads();

    // phase B: MFMA over virtual K=256 ([x_row | agg_row])
    const int nidx = lane & 15, quad = lane >> 4;
    int arow = rbase + w * 16 + nidx;
    if (arow > NN - 1) arow = NN - 1;          // clamped rows never stored
    const u16* xu = &Xb[(size_t)arow * K];
    const u16* grow = &aggT[(w * 16 + nidx) * RS];
    f32x4 acc[CT] = {};
#pragma unroll
    for (int s = 0; s < KV; ++s) {
        s16x8 a = (s < 4) ? *(const s16x8*)&xu[s * 32 + quad * 8]
                          : *(const s16x8*)&grow[(s - 4) * 32 + quad * 8];
#pragma unroll
        for (int c = 0; c < CT; ++c) {
            s16x8 b = *(const s16x8*)&WT[((c * KV + s) * 64 + lane) * 8];
            acc[c] = __builtin_amdgcn_mfma_f32_16x16x32_bf16(a, b, acc[c], 0, 0, 0);
        }
    }
#pragma unroll
    for (int c = 0; c < CT; ++c) {
        int col = c * 16 + nidx;
        float bv = biasf[col];
#pragma unroll
        for (int r = 0; r < 4; ++r) {
            int orow = rbase + w * 16 + quad * 4 + r;
            if (orow < NN) {
                float hv = fmaxf(acc[c][r] + bv, 0.f);
                Hb[(size_t)orow * CO + col] = f2bf(hv);
                if (DUALOUT) Hf[(size_t)orow * CO + col] = hv;   // fp32 h output
            }
        }
    }
}

// ---------------- edge scoring via MFMA from bf16 H2 copy; fp32 score output ----------------
__global__ __launch_bounds__(256) void k_edge(const u16* __restrict__ H2,
                                              const u16* __restrict__ WTM,
                                              const int* __restrict__ es, const int* __restrict__ ed,
                                              const float* __restrict__ blob,
                                              float* __restrict__ out) {
    constexpr int RS = 136;
    __shared__ __align__(16) u16 at[64 * RS];
    const int t = threadIdx.x, lane = t & 63, w = t >> 6;
    const int ebase = blockIdx.x * 64 + w * 16;
    {
        const int le = lane >> 2, p = lane & 3;
        const int e = ebase + le;
        int node = (p < 2) ? es[e] : ed[e];
        node = clampi(node, NN - 1);
        const u16* row = H2 + (size_t)node * 64 + (p & 1) * 32;
        u16* drow = &at[(w * 16 + le) * RS + (p >> 1) * 64 + (p & 1) * 32];
        *(uint4*)&drow[0]  = *(const uint4*)&row[0];
        *(uint4*)&drow[8]  = *(const uint4*)&row[8];
        *(uint4*)&drow[16] = *(const uint4*)&row[16];
        *(uint4*)&drow[24] = *(const uint4*)&row[24];
    }
    __syncthreads();

    const int nidx = lane & 15, quad = lane >> 4;
    const u16* arow = &at[(w * 16 + nidx) * RS];
    f32x4 acc[8] = {};
#pragma unroll
    for (int s = 0; s < 4; ++s) {
        s16x8 a = *(const s16x8*)&arow[s * 32 + quad * 8];
#pragma unroll
        for (int c = 0; c < 8; ++c) {
            s16x8 b = *(const s16x8*)&WTM[((c * 4 + s) * 64 + lane) * 8];
            acc[c] = __builtin_amdgcn_mfma_f32_16x16x32_bf16(a, b, acc[c], 0, 0, 0);
        }
    }
    float sum[4] = {0.f, 0.f, 0.f, 0.f};
#pragma unroll
    for (int c = 0; c < 8; ++c) {
        int col = c * 16 + nidx;
        float bb = blob[192 + col], ww = blob[320 + col];
#pragma unroll
        for (int r = 0; r < 4; ++r)
            sum[r] += fmaxf(acc[c][r] + bb, 0.f) * ww;
    }
#pragma unroll
    for (int r = 0; r < 4; ++r) {
        sum[r] += __shfl_xor(sum[r], 1, 64);
        sum[r] += __shfl_xor(sum[r], 2, 64);
        sum[r] += __shfl_xor(sum[r], 4, 64);
        sum[r] += __shfl_xor(sum[r], 8, 64);
    }
    if (nidx == 0) {
        float bb2 = blob[448];
#pragma unroll
        for (int r = 0; r < 4; ++r) {
            float x = sum[r] + bb2;
            out[ebase + quad * 4 + r] = 1.f / (1.f + __expf(-x));   // fp32 score
        }
    }
}

extern "C" void kernel_launch(void* const* d_in, const int* in_sizes, int n_in,
                              void* d_out, int out_size, void* d_ws, size_t ws_size,
                              hipStream_t stream) {
    const float* X      = (const float*)d_in[0];
    const int*   esrc   = (const int*)d_in[1];
    const int*   edst   = (const int*)d_in[2];
    const int*   ssrc   = (const int*)d_in[3];
    const int*   sdst   = (const int*)d_in[4];
    const float* Wself1 = (const float*)d_in[5];
    const float* Wneigh1= (const float*)d_in[6];
    const float* b1     = (const float*)d_in[7];
    const float* Wself2 = (const float*)d_in[8];
    const float* Wneigh2= (const float*)d_in[9];
    const float* b2     = (const float*)d_in[10];
    const float* Wmlp1  = (const float*)d_in[11];
    const float* bmlp1  = (const float*)d_in[12];
    const float* Wmlp2  = (const float*)d_in[13];
    const float* bmlp2  = (const float*)d_in[14];

    // ---- workspace (probe-verified ws_size >= 50 MB): peak 45.34 MB ----
    char* ws = (char*)d_ws;
    int*   offs = (int*)(ws + 0);             //   400,004 -> pad 400,128
    int*   csr  = (int*)(ws + 400128);        // 6,400,000 -> 6,800,128
    u16*   WTM  = (u16*)(ws + 6800128);       //    32,768 -> 6,832,896
    u16*   WT1  = (u16*)(ws + 6832896);       //    65,536 -> 6,898,432
    u16*   WT2  = (u16*)(ws + 6898432);       //    32,768 -> 6,931,200
    float* blob = (float*)(ws + 6931200);     //     1,796 -> pad 6,933,504
    u16*   H1   = (u16*)(ws + 6933504);       // 25,600,000 -> 32,533,504 (bf16 intern)
    u16*   H2b  = (u16*)(ws + 32533504);      // 12,800,000 -> 45,333,504 (bf16 copy of h)
    int*   deg  = (int*)(ws + 6933504);       // aliases H1 (dead before H1 written)
    int*   cur  = (int*)(ws + 7333504);       // aliases H1 + 400 KB
    int*   part = (int*)(ws + 7733504);       // aliases H1 + 800 KB (scan partials, 391*4 B)

    // ---- OUTPUT: fp32 buffer, out_size=8M floats: [score 1.6M | h 6.4M] ----
    float* outScore = (float*)d_out;               // [EE2]
    float* Hf       = (float*)d_out + EE2;         // [NN*64]
    // X as bf16, parked in d_out's h-region (dead until layer-2's Hf write):
    u16*   Xb       = (u16*)((char*)d_out + 6400000);   // 25.6 MB, ends at 32 MB

    k_cast<<<(NN * 128 / 4 + 255) / 256, 256, 0, stream>>>(X, Xb);
    hipMemsetAsync(deg, 0, NN * sizeof(int), stream);
    k_deg <<<(EE1 + 255) / 256, 256, 0, stream>>>(edst, deg);
    k_scan1<<<NBLK_SCAN, 256, 0, stream>>>(deg, part);
    k_scan2<<<1, 512, 0, stream>>>(part);
    k_scan3<<<NBLK_SCAN, 256, 0, stream>>>(deg, part, offs, cur);
    k_fill<<<(EE1 + 255) / 256, 256, 0, stream>>>(esrc, edst, cur, csr);
    k_prep<<<256, 256, 0, stream>>>(Wself1, Wneigh1, Wself2, Wneigh2, Wmlp1, WT1, WT2, WTM);
    k_bias<<<1, 512, 0, stream>>>(b1, b2, bmlp1, Wmlp2, bmlp2, blob);

    const int nblk = (NN + 63) / 64;
    k_layer<128, false><<<nblk, 256, 0, stream>>>(Xb, WT1, offs, csr, blob,       H1,  nullptr);
    k_layer<64,  true> <<<nblk, 256, 0, stream>>>(H1, WT2, offs, csr, blob + 128, H2b, Hf);
    k_edge<<<EE2 / 64, 256, 0, stream>>>(H2b, WTM, ssrc, sdst, blob, outScore);
}